// Round 3
// baseline (242.197 us; speedup 1.0000x reference)
//
#include <hip/hip_runtime.h>

#define SRATE 44100.0
#ifndef M_PI
#define M_PI 3.14159265358979323846
#endif

#define CHUNK 32                  // samples per chunk (per thread)
#define THREADS 256               // chunks per block
#define NBLK 2048                 // 524288 chunks / 256
#define BLK_PER_CH 256            // blocks per channel (2097152 / 8192)
#define MSTRIDE 12                // LDS matrix row stride (48B, 16B-aligned rows)

// Per-block table build: coefficients (double -> float) and 8 fp32 transition
// matrices A^(2^k), k = klo..klo+7, all in this block's LDS. Replaces the old
// separate k0 kernel (saves a launch; overlaps with in-flight x loads).
__device__ __forceinline__ void build_block_tables(const float* __restrict__ eqp,
                                                   double* cfd, double* Md,
                                                   float* cfs, float* Mf, int klo) {
    int t = threadIdx.x;
    if (t < 5) {
        int i = t;
        double g  = (double)eqp[i*3 + 0];
        double fc = (double)eqp[i*3 + 1];
        double q  = (double)eqp[i*3 + 2];
        double A  = pow(10.0, g / 40.0);
        double w0 = 2.0 * M_PI * (fc / SRATE);
        double al = sin(w0) / (2.0 * q);
        double c  = cos(w0);
        double b0, b1, b2, a0, a1, a2;
        if (i == 0 || i == 4) {
            double sgn = (i == 4) ? 1.0 : -1.0;
            double sA = sqrt(A);
            b0 = A * ((A + 1.0) + sgn * (A - 1.0) * c + 2.0 * sA * al);
            b1 = -2.0 * sgn * A * ((A - 1.0) + sgn * (A + 1.0) * c);
            b2 = A * ((A + 1.0) + sgn * (A - 1.0) * c - 2.0 * sA * al);
            a0 = (A + 1.0) - sgn * (A - 1.0) * c + 2.0 * sA * al;
            a1 = 2.0 * sgn * ((A - 1.0) - sgn * (A + 1.0) * c);
            a2 = (A + 1.0) - sgn * (A - 1.0) * c - 2.0 * sA * al;
        } else {
            b0 = 1.0 + al * A; b1 = -2.0 * c; b2 = 1.0 - al * A;
            a0 = 1.0 + al / A; a1 = -2.0 * c; a2 = 1.0 - al / A;
        }
        cfd[i*5+0] = b0/a0; cfd[i*5+1] = b1/a0; cfd[i*5+2] = b2/a0;
        cfd[i*5+3] = a1/a0; cfd[i*5+4] = a2/a0;
        cfs[i*5+0] = (float)(b0/a0); cfs[i*5+1] = (float)(b1/a0);
        cfs[i*5+2] = (float)(b2/a0); cfs[i*5+3] = (float)(a1/a0);
        cfs[i*5+4] = (float)(a2/a0);
    }
    __syncthreads();

    // A: column j = one cascade step applied to unit state e_j with x=0
    if (t < 10) {
        double s[10];
        #pragma unroll
        for (int k = 0; k < 10; k++) s[k] = (k == t) ? 1.0 : 0.0;
        double u = 0.0;
        #pragma unroll
        for (int i = 0; i < 5; i++) {
            double y   = cfd[i*5+0] * u + s[2*i];
            double s1n = cfd[i*5+1] * u - cfd[i*5+3] * y + s[2*i+1];
            double s2n = cfd[i*5+2] * u - cfd[i*5+4] * y;
            s[2*i] = s1n; s[2*i+1] = s2n; u = y;
        }
        for (int r = 0; r < 10; r++) Md[r*10 + t] = s[r];
    }
    __syncthreads();

    // repeated squaring: after k squarings, Md = A^(2^k); store k in [klo, klo+8)
    for (int k = 1; k <= 20; k++) {
        double val = 0.0;
        if (t < 100) {
            int r = t / 10, c = t % 10;
            #pragma unroll
            for (int j = 0; j < 10; j++) val += Md[r*10 + j] * Md[j*10 + c];
        }
        __syncthreads();
        if (t < 100) {
            Md[t] = val;
            int d = k - klo;
            if (d >= 0 && d < 8)
                Mf[d*120 + (t/10)*MSTRIDE + (t%10)] = (float)val;
        }
        __syncthreads();
    }
}

// kA: zero-state cascade per 32-sample chunk (direct register loads, no input
// staging, no barriers in the cascade), then Kogge-Stone over the block's 256
// chunks with LDS-broadcast matrices. Writes exclusive prefixes + aggregate.
__global__ __launch_bounds__(256, 6) void kA(const float* __restrict__ x,
                                             const float* __restrict__ eqp,
                                             float* __restrict__ ibuf,
                                             float* __restrict__ abuf) {
    __shared__ double cfd[25];
    __shared__ double Md[100];
    __shared__ float  cfs[25];
    __shared__ __align__(16) float Mf[960];
    __shared__ float  buf[256][11];

    int t = threadIdx.x, b = blockIdx.x;

    // issue x loads immediately; they complete under the serial table build
    const float4* x4 = (const float4*)x + ((size_t)b * 256 + t) * 8;
    float4 rr[8];
    #pragma unroll
    for (int j = 0; j < 8; j++) rr[j] = x4[j];

    build_block_tables(eqp, cfd, Md, cfs, Mf, 5);   // P_d = A^(32*2^d)

    float cb0[5], cb1[5], cb2[5], ca1[5], ca2[5];
    #pragma unroll
    for (int i = 0; i < 5; i++) {
        cb0[i] = cfs[i*5+0]; cb1[i] = cfs[i*5+1]; cb2[i] = cfs[i*5+2];
        ca1[i] = cfs[i*5+3]; ca2[i] = cfs[i*5+4];
    }

    float s[10];
    #pragma unroll
    for (int k = 0; k < 10; k++) s[k] = 0.0f;

    #pragma unroll
    for (int j = 0; j < 8; j++) {
        float xs[4] = { rr[j].x, rr[j].y, rr[j].z, rr[j].w };
        #pragma unroll
        for (int i = 0; i < 4; i++) {
            float u = xs[i];
            #pragma unroll
            for (int st = 0; st < 5; st++) {
                float y  = fmaf(cb0[st], u, s[2*st]);
                float t1 = fmaf(cb1[st], u, s[2*st+1]);
                s[2*st+1] = fmaf(-ca2[st], y, cb2[st] * u);
                s[2*st]   = fmaf(-ca1[st], y, t1);
                u = y;
            }
        }
    }

    // Kogge-Stone over 256 chunks, 8 levels
    #pragma unroll
    for (int r = 0; r < 10; r++) buf[t][r] = s[r];
    __syncthreads();

    #pragma unroll 1
    for (int d = 0; d < 8; d++) {
        int lvl = d * 120;
        int src = t - (1 << d);
        int sc  = src < 0 ? 0 : src;
        float bs[10];
        #pragma unroll
        for (int r = 0; r < 10; r++) bs[r] = buf[sc][r];
        float nv[10];
        #pragma unroll
        for (int r = 0; r < 10; r++) {
            float acc = s[r];
            #pragma unroll
            for (int k = 0; k < 10; k++)
                acc = fmaf(Mf[lvl + r*MSTRIDE + k], bs[k], acc);
            nv[r] = acc;
        }
        __syncthreads();
        bool act = src >= 0;
        #pragma unroll
        for (int r = 0; r < 10; r++) { s[r] = act ? nv[r] : s[r]; buf[t][r] = s[r]; }
        __syncthreads();
    }

    #pragma unroll
    for (int r = 0; r < 10; r++)
        ibuf[(size_t)b * 2560 + r * 256 + t] = (t > 0) ? buf[t-1][r] : 0.0f;
    if (t == 255) {
        #pragma unroll
        for (int r = 0; r < 10; r++) abuf[b * 10 + r] = s[r];
    }
}

// kB: one block per channel; KS scan of the channel's 256 block aggregates.
__global__ __launch_bounds__(256) void kB(const float* __restrict__ eqp,
                                          const float* __restrict__ abuf,
                                          float* __restrict__ bbuf) {
    __shared__ double cfd[25];
    __shared__ double Md[100];
    __shared__ float  cfs[25];
    __shared__ __align__(16) float Mf[960];
    __shared__ float  buf[256][11];

    int t = threadIdx.x, ch = blockIdx.x;
    int g = ch * 256 + t;

    float v[10];
    #pragma unroll
    for (int r = 0; r < 10; r++) v[r] = abuf[g * 10 + r];

    build_block_tables(eqp, cfd, Md, cfs, Mf, 13);  // Q_e = A^(8192*2^e)

    #pragma unroll
    for (int r = 0; r < 10; r++) buf[t][r] = v[r];
    __syncthreads();

    #pragma unroll 1
    for (int e = 0; e < 8; e++) {
        int lvl = e * 120;
        int src = t - (1 << e);
        int sc  = src < 0 ? 0 : src;
        float bs[10];
        #pragma unroll
        for (int r = 0; r < 10; r++) bs[r] = buf[sc][r];
        float nv[10];
        #pragma unroll
        for (int r = 0; r < 10; r++) {
            float acc = v[r];
            #pragma unroll
            for (int k = 0; k < 10; k++)
                acc = fmaf(Mf[lvl + r*MSTRIDE + k], bs[k], acc);
            nv[r] = acc;
        }
        __syncthreads();
        bool act = src >= 0;
        #pragma unroll
        for (int r = 0; r < 10; r++) { v[r] = act ? nv[r] : v[r]; buf[t][r] = v[r]; }
        __syncthreads();
    }

    #pragma unroll
    for (int r = 0; r < 10; r++)
        bbuf[g * 10 + r] = (t > 0) ? buf[t-1][r] : 0.0f;
}

// kC: true init = ibuf local prefix + A^(32*t) * bbuf[block] (binary decomp,
// LDS-broadcast matrices), re-run cascade, direct register stores.
__global__ __launch_bounds__(256, 6) void kC(const float* __restrict__ x,
                                             const float* __restrict__ eqp,
                                             const float* __restrict__ ibuf,
                                             const float* __restrict__ bbuf,
                                             float* __restrict__ out) {
    __shared__ double cfd[25];
    __shared__ double Md[100];
    __shared__ float  cfs[25];
    __shared__ __align__(16) float Mf[960];

    int t = threadIdx.x, b = blockIdx.x;

    const float4* x4 = (const float4*)x + ((size_t)b * 256 + t) * 8;
    float4 rr[8];
    #pragma unroll
    for (int j = 0; j < 8; j++) rr[j] = x4[j];

    float sp[10];
    #pragma unroll
    for (int r = 0; r < 10; r++)
        sp[r] = ibuf[(size_t)b * 2560 + r * 256 + t];
    float bp[10];
    #pragma unroll
    for (int r = 0; r < 10; r++) bp[r] = bbuf[b * 10 + r];

    build_block_tables(eqp, cfd, Md, cfs, Mf, 5);   // P_d = A^(32*2^d)

    float cb0[5], cb1[5], cb2[5], ca1[5], ca2[5];
    #pragma unroll
    for (int i = 0; i < 5; i++) {
        cb0[i] = cfs[i*5+0]; cb1[i] = cfs[i*5+1]; cb2[i] = cfs[i*5+2];
        ca1[i] = cfs[i*5+3]; ca2[i] = cfs[i*5+4];
    }

    // binary decomposition: bp = A^(32*t) * Bpre
    #pragma unroll 1
    for (int d = 0; d < 8; d++) {
        int lvl = d * 120;
        float wv[10];
        #pragma unroll
        for (int r = 0; r < 10; r++) {
            float acc = 0.0f;
            #pragma unroll
            for (int k = 0; k < 10; k++)
                acc = fmaf(Mf[lvl + r*MSTRIDE + k], bp[k], acc);
            wv[r] = acc;
        }
        bool bit = (t >> d) & 1;
        #pragma unroll
        for (int r = 0; r < 10; r++) bp[r] = bit ? wv[r] : bp[r];
    }

    float s[10];
    #pragma unroll
    for (int r = 0; r < 10; r++) s[r] = sp[r] + bp[r];

    #pragma unroll
    for (int j = 0; j < 8; j++) {
        float xs[4] = { rr[j].x, rr[j].y, rr[j].z, rr[j].w };
        #pragma unroll
        for (int i = 0; i < 4; i++) {
            float u = xs[i];
            #pragma unroll
            for (int st = 0; st < 5; st++) {
                float y  = fmaf(cb0[st], u, s[2*st]);
                float t1 = fmaf(cb1[st], u, s[2*st+1]);
                s[2*st+1] = fmaf(-ca2[st], y, cb2[st] * u);
                s[2*st]   = fmaf(-ca1[st], y, t1);
                u = y;
            }
            xs[i] = u;
        }
        rr[j] = make_float4(xs[0], xs[1], xs[2], xs[3]);
    }

    float4* o4 = (float4*)out + ((size_t)b * 256 + t) * 8;
    #pragma unroll
    for (int j = 0; j < 8; j++) o4[j] = rr[j];
}

extern "C" void kernel_launch(void* const* d_in, const int* in_sizes, int n_in,
                              void* d_out, int out_size, void* d_ws, size_t ws_size,
                              hipStream_t stream) {
    const float* x   = (const float*)d_in[0];
    const float* eqp = (const float*)d_in[1];
    float* out = (float*)d_out;
    char* ws = (char*)d_ws;

    float* ibuf = (float*)ws;                               // 2048*2560 floats = 20.97 MB
    float* abuf = (float*)(ws + 20971520);                  // 2048*10 floats
    float* bbuf = (float*)(ws + 20971520 + 81920);          // 2048*10 floats

    hipLaunchKernelGGL(kA, dim3(NBLK), dim3(THREADS), 0, stream, x, eqp, ibuf, abuf);
    hipLaunchKernelGGL(kB, dim3(8),    dim3(THREADS), 0, stream, eqp, abuf, bbuf);
    hipLaunchKernelGGL(kC, dim3(NBLK), dim3(THREADS), 0, stream, x, eqp, ibuf, bbuf, out);
}

// Round 4
// 190.101 us; speedup vs baseline: 1.2740x; 1.2740x over previous
//
#include <hip/hip_runtime.h>

#define SRATE 44100.0
#ifndef M_PI
#define M_PI 3.14159265358979323846
#endif

#define THREADS 256               // chunks per block
#define NBLK 2048                 // 524288 chunks / 256 (block = 8192 samples)
#define STRIDE 17                 // LDS staging row stride (floats)

// Triangular matvec: acc[r] += sum_{k < 2*(r/2)+2} M[r*10+k] * bs[k].
// A (cascade state transition) is block-lower-triangular; powers stay so.
__device__ __forceinline__ void matvec_tri(const float* __restrict__ M,
                                           const float* bs, float* acc) {
    #pragma unroll
    for (int i = 0; i < 5; i++) {
        #pragma unroll
        for (int h = 0; h < 2; h++) {
            const int r = 2*i + h;
            float a = acc[r];
            #pragma unroll
            for (int k = 0; k < 2*i + 2; k++)
                a = fmaf(M[r*10 + k], bs[k], a);
            acc[r] = a;
        }
    }
}

__device__ __forceinline__ float cascade5(const float* cb0, const float* cb1,
                                          const float* cb2, const float* ca1,
                                          const float* ca2, float* s, float u) {
    #pragma unroll
    for (int st = 0; st < 5; st++) {
        float y  = fmaf(cb0[st], u, s[2*st]);
        float t1 = fmaf(cb1[st], u, s[2*st+1]);
        s[2*st+1] = fmaf(-ca2[st], y, cb2[st] * u);
        s[2*st]   = fmaf(-ca1[st], y, t1);
        u = y;
    }
    return u;
}

// K0: coefficients + 16 fp32 matrix powers P_d = A^(32*2^d) = A^(2^(5+d)),
// d = 0..15. kA/kC use d<8 (intra-block scan + decomp); kB uses d=8..15.
__global__ __launch_bounds__(128) void k0_setup(const float* __restrict__ eqp,
                                                float* __restrict__ coef_f,
                                                float* __restrict__ mats_f) {
    __shared__ double cfd[25];
    __shared__ double Md[100];
    int t = threadIdx.x;

    if (t < 5) {
        int i = t;
        double g  = (double)eqp[i*3 + 0];
        double fc = (double)eqp[i*3 + 1];
        double q  = (double)eqp[i*3 + 2];
        double A  = pow(10.0, g / 40.0);
        double w0 = 2.0 * M_PI * (fc / SRATE);
        double al = sin(w0) / (2.0 * q);
        double c  = cos(w0);
        double b0, b1, b2, a0, a1, a2;
        if (i == 0 || i == 4) {
            double sgn = (i == 4) ? 1.0 : -1.0;
            double sA = sqrt(A);
            b0 = A * ((A + 1.0) + sgn * (A - 1.0) * c + 2.0 * sA * al);
            b1 = -2.0 * sgn * A * ((A - 1.0) + sgn * (A + 1.0) * c);
            b2 = A * ((A + 1.0) + sgn * (A - 1.0) * c - 2.0 * sA * al);
            a0 = (A + 1.0) - sgn * (A - 1.0) * c + 2.0 * sA * al;
            a1 = 2.0 * sgn * ((A - 1.0) - sgn * (A + 1.0) * c);
            a2 = (A + 1.0) - sgn * (A - 1.0) * c - 2.0 * sA * al;
        } else {
            b0 = 1.0 + al * A; b1 = -2.0 * c; b2 = 1.0 - al * A;
            a0 = 1.0 + al / A; a1 = -2.0 * c; a2 = 1.0 - al / A;
        }
        cfd[i*5+0] = b0/a0; cfd[i*5+1] = b1/a0; cfd[i*5+2] = b2/a0;
        cfd[i*5+3] = a1/a0; cfd[i*5+4] = a2/a0;
        coef_f[i*5+0] = (float)(b0/a0); coef_f[i*5+1] = (float)(b1/a0);
        coef_f[i*5+2] = (float)(b2/a0); coef_f[i*5+3] = (float)(a1/a0);
        coef_f[i*5+4] = (float)(a2/a0);
    }
    __syncthreads();

    // A: column j = one cascade step applied to unit state e_j with x=0
    if (t < 10) {
        double s[10];
        #pragma unroll
        for (int k = 0; k < 10; k++) s[k] = (k == t) ? 1.0 : 0.0;
        double u = 0.0;
        #pragma unroll
        for (int i = 0; i < 5; i++) {
            double y   = cfd[i*5+0] * u + s[2*i];
            double s1n = cfd[i*5+1] * u - cfd[i*5+3] * y + s[2*i+1];
            double s2n = cfd[i*5+2] * u - cfd[i*5+4] * y;
            s[2*i] = s1n; s[2*i+1] = s2n; u = y;
        }
        for (int r = 0; r < 10; r++) Md[r*10 + t] = s[r];
    }
    __syncthreads();

    // after k squarings Md = A^(2^k); store k = 5..20
    for (int k = 1; k <= 20; k++) {
        double val = 0.0;
        if (t < 100) {
            int r = t / 10, c = t % 10;
            #pragma unroll
            for (int j = 0; j < 10; j++) val += Md[r*10 + j] * Md[j*10 + c];
        }
        __syncthreads();
        if (t < 100) {
            Md[t] = val;
            int d = k - 5;
            if (d >= 0 && d < 16) mats_f[d*100 + t] = (float)val;
        }
        __syncthreads();
    }
}

// kA: zero-state cascade per 32-sample chunk (LDS-transposed coalesced input,
// single 17.4 KB window buffer), then 8-level Kogge-Stone over the block's 256
// chunks (triangular matvecs, LDS-broadcast mats). Writes exclusive per-chunk
// prefixes (ibuf) + block aggregate (abuf).
__global__ __launch_bounds__(256, 6) void kA(const float* __restrict__ x,
                                             const float* __restrict__ coef,
                                             const float* __restrict__ mats,
                                             float* __restrict__ ibuf,
                                             float* __restrict__ abuf) {
    __shared__ union {
        float stage[256 * STRIDE];      // 17408 B
        float buf[256][11];             // 11264 B (time-disjoint overlay)
    } sm;
    __shared__ float Mf[800];
    __shared__ float cfs[25];
    const int t = threadIdx.x, b = blockIdx.x;
    const int cb = t >> 2, q = t & 3;
    const float4* x4 = (const float4*)x + (size_t)b * 2048;

    // window 0 prefetch (flies under table loads)
    float4 rr[4];
    #pragma unroll
    for (int k = 0; k < 4; k++) rr[k] = x4[(cb + 64*k)*8 + q];

    for (int i = t; i < 800; i += 256) Mf[i] = mats[i];
    if (t < 25) cfs[t] = coef[t];

    #pragma unroll
    for (int k = 0; k < 4; k++) {
        int o = (cb + 64*k)*STRIDE + q*4;
        sm.stage[o+0]=rr[k].x; sm.stage[o+1]=rr[k].y;
        sm.stage[o+2]=rr[k].z; sm.stage[o+3]=rr[k].w;
    }
    __syncthreads();                           // stage w0 + Mf + cfs ready

    // prefetch window 1 now; completes under w0 compute
    #pragma unroll
    for (int k = 0; k < 4; k++) rr[k] = x4[(cb + 64*k)*8 + 4 + q];

    float cb0[5],cb1[5],cb2[5],ca1[5],ca2[5];
    #pragma unroll
    for (int i = 0; i < 5; i++) {
        cb0[i]=cfs[i*5+0]; cb1[i]=cfs[i*5+1]; cb2[i]=cfs[i*5+2];
        ca1[i]=cfs[i*5+3]; ca2[i]=cfs[i*5+4];
    }

    float s[10];
    #pragma unroll
    for (int k = 0; k < 10; k++) s[k] = 0.0f;

    {   // window 0: samples 0..15
        const float* row = sm.stage + t*STRIDE;
        #pragma unroll
        for (int i = 0; i < 16; i++) (void)cascade5(cb0,cb1,cb2,ca1,ca2, s, row[i]);
    }
    __syncthreads();                           // all w0 reads done
    #pragma unroll
    for (int k = 0; k < 4; k++) {
        int o = (cb + 64*k)*STRIDE + q*4;
        sm.stage[o+0]=rr[k].x; sm.stage[o+1]=rr[k].y;
        sm.stage[o+2]=rr[k].z; sm.stage[o+3]=rr[k].w;
    }
    __syncthreads();                           // stage w1 ready
    {   // window 1: samples 16..31
        const float* row = sm.stage + t*STRIDE;
        #pragma unroll
        for (int i = 0; i < 16; i++) (void)cascade5(cb0,cb1,cb2,ca1,ca2, s, row[i]);
    }
    __syncthreads();                           // stage reads done -> buf overlay safe

    // 8-level Kogge-Stone over 256 chunks
    #pragma unroll
    for (int r = 0; r < 10; r++) sm.buf[t][r] = s[r];
    __syncthreads();

    #pragma unroll 1
    for (int d = 0; d < 8; d++) {
        int src = t - (1 << d);
        int sc  = src < 0 ? 0 : src;
        float bs[10], nv[10];
        #pragma unroll
        for (int r = 0; r < 10; r++) { bs[r] = sm.buf[sc][r]; nv[r] = s[r]; }
        matvec_tri(&Mf[d*100], bs, nv);
        __syncthreads();
        bool act = src >= 0;
        #pragma unroll
        for (int r = 0; r < 10; r++) { s[r] = act ? nv[r] : s[r]; sm.buf[t][r] = s[r]; }
        __syncthreads();
    }

    #pragma unroll
    for (int r = 0; r < 10; r++)
        ibuf[(size_t)b * 2560 + r * 256 + t] = (t > 0) ? sm.buf[t-1][r] : 0.0f;
    if (t == 255) {
        #pragma unroll
        for (int r = 0; r < 10; r++) abuf[b * 10 + r] = s[r];
    }
}

// kB: one block per channel; KS scan of the channel's 256 block aggregates
// with Q_e = A^(8192*2^e) = P_{8+e}. Writes exclusive block prefixes.
__global__ __launch_bounds__(256) void kB(const float* __restrict__ mats,
                                          const float* __restrict__ abuf,
                                          float* __restrict__ bbuf) {
    __shared__ float Qf[800];
    __shared__ float buf[256][11];
    const int t = threadIdx.x, ch = blockIdx.x;
    const int g = ch * 256 + t;

    for (int i = t; i < 800; i += 256) Qf[i] = mats[800 + i];

    float v[10];
    #pragma unroll
    for (int r = 0; r < 10; r++) { v[r] = abuf[g * 10 + r]; buf[t][r] = v[r]; }
    __syncthreads();

    #pragma unroll 1
    for (int e = 0; e < 8; e++) {
        int src = t - (1 << e);
        int sc  = src < 0 ? 0 : src;
        float bs[10], nv[10];
        #pragma unroll
        for (int r = 0; r < 10; r++) { bs[r] = buf[sc][r]; nv[r] = v[r]; }
        matvec_tri(&Qf[e*100], bs, nv);
        __syncthreads();
        bool act = src >= 0;
        #pragma unroll
        for (int r = 0; r < 10; r++) { v[r] = act ? nv[r] : v[r]; buf[t][r] = v[r]; }
        __syncthreads();
    }

    #pragma unroll
    for (int r = 0; r < 10; r++)
        bbuf[g * 10 + r] = (t > 0) ? buf[t-1][r] : 0.0f;
}

// kC: init = ibuf[chunk] + A^(32*t)*bbuf[block] (8 triangular decomp matvecs),
// re-run cascade writing y in place in the staging window, coalesced coop-store.
__global__ __launch_bounds__(256, 6) void kC(const float* __restrict__ x,
                                             const float* __restrict__ coef,
                                             const float* __restrict__ mats,
                                             const float* __restrict__ ibuf,
                                             const float* __restrict__ bbuf,
                                             float* __restrict__ out) {
    __shared__ float stage[256 * STRIDE];      // 17408 B, in+out reuse
    __shared__ float Mf[800];
    __shared__ float cfs[25];
    const int t = threadIdx.x, b = blockIdx.x;
    const int cb = t >> 2, q = t & 3;
    const float4* x4 = (const float4*)x + (size_t)b * 2048;
    float4* o4 = (float4*)out + (size_t)b * 2048;

    float4 rr[4];
    #pragma unroll
    for (int k = 0; k < 4; k++) rr[k] = x4[(cb + 64*k)*8 + q];

    float sp[10];
    #pragma unroll
    for (int r = 0; r < 10; r++) sp[r] = ibuf[(size_t)b * 2560 + r * 256 + t];
    float bp[10];
    #pragma unroll
    for (int r = 0; r < 10; r++) bp[r] = bbuf[b * 10 + r];

    for (int i = t; i < 800; i += 256) Mf[i] = mats[i];
    if (t < 25) cfs[t] = coef[t];

    #pragma unroll
    for (int k = 0; k < 4; k++) {
        int o = (cb + 64*k)*STRIDE + q*4;
        stage[o+0]=rr[k].x; stage[o+1]=rr[k].y;
        stage[o+2]=rr[k].z; stage[o+3]=rr[k].w;
    }
    __syncthreads();                           // stage w0 + Mf + cfs ready

    // prefetch window 1; completes under decomp + w0 compute
    #pragma unroll
    for (int k = 0; k < 4; k++) rr[k] = x4[(cb + 64*k)*8 + 4 + q];

    float cb0[5],cb1[5],cb2[5],ca1[5],ca2[5];
    #pragma unroll
    for (int i = 0; i < 5; i++) {
        cb0[i]=cfs[i*5+0]; cb1[i]=cfs[i*5+1]; cb2[i]=cfs[i*5+2];
        ca1[i]=cfs[i*5+3]; ca2[i]=cfs[i*5+4];
    }

    // binary decomposition: bp = A^(32*t) * Bpre
    #pragma unroll 1
    for (int d = 0; d < 8; d++) {
        float wv[10];
        #pragma unroll
        for (int r = 0; r < 10; r++) wv[r] = 0.0f;
        matvec_tri(&Mf[d*100], bp, wv);
        bool bit = (t >> d) & 1;
        #pragma unroll
        for (int r = 0; r < 10; r++) bp[r] = bit ? wv[r] : bp[r];
    }
    float s[10];
    #pragma unroll
    for (int r = 0; r < 10; r++) s[r] = sp[r] + bp[r];

    {   // window 0: compute in place, then coop-store
        float* row = stage + t*STRIDE;
        #pragma unroll
        for (int i = 0; i < 16; i++) row[i] = cascade5(cb0,cb1,cb2,ca1,ca2, s, row[i]);
    }
    __syncthreads();                           // y rows visible
    #pragma unroll
    for (int k = 0; k < 4; k++) {
        int o = (cb + 64*k)*STRIDE + q*4;
        o4[(cb + 64*k)*8 + q] = make_float4(stage[o+0], stage[o+1], stage[o+2], stage[o+3]);
    }
    __syncthreads();                           // store reads done -> w1 overwrite safe
    #pragma unroll
    for (int k = 0; k < 4; k++) {
        int o = (cb + 64*k)*STRIDE + q*4;
        stage[o+0]=rr[k].x; stage[o+1]=rr[k].y;
        stage[o+2]=rr[k].z; stage[o+3]=rr[k].w;
    }
    __syncthreads();                           // stage w1 ready
    {   // window 1
        float* row = stage + t*STRIDE;
        #pragma unroll
        for (int i = 0; i < 16; i++) row[i] = cascade5(cb0,cb1,cb2,ca1,ca2, s, row[i]);
    }
    __syncthreads();                           // y rows visible
    #pragma unroll
    for (int k = 0; k < 4; k++) {
        int o = (cb + 64*k)*STRIDE + q*4;
        o4[(cb + 64*k)*8 + 4 + q] = make_float4(stage[o+0], stage[o+1], stage[o+2], stage[o+3]);
    }
}

extern "C" void kernel_launch(void* const* d_in, const int* in_sizes, int n_in,
                              void* d_out, int out_size, void* d_ws, size_t ws_size,
                              hipStream_t stream) {
    const float* x   = (const float*)d_in[0];
    const float* eqp = (const float*)d_in[1];
    float* out = (float*)d_out;
    char* ws = (char*)d_ws;

    float* coef_f = (float*)ws;                              // 25 floats
    float* mats_f = (float*)(ws + 256);                      // 1600 floats
    float* ibuf   = (float*)(ws + 8192);                     // 2048*2560 fl = 20.97 MB
    float* abuf   = (float*)(ws + 8192 + 20971520);          // 2048*10 floats
    float* bbuf   = (float*)(ws + 8192 + 20971520 + 81920);  // 2048*10 floats

    hipLaunchKernelGGL(k0_setup, dim3(1), dim3(128), 0, stream, eqp, coef_f, mats_f);
    hipLaunchKernelGGL(kA, dim3(NBLK), dim3(THREADS), 0, stream, x, coef_f, mats_f, ibuf, abuf);
    hipLaunchKernelGGL(kB, dim3(8),    dim3(THREADS), 0, stream, mats_f, abuf, bbuf);
    hipLaunchKernelGGL(kC, dim3(NBLK), dim3(THREADS), 0, stream,
                       x, coef_f, mats_f, ibuf, bbuf, out);
}